// Round 5
// baseline (254.626 us; speedup 1.0000x reference)
//
#include <hip/hip_runtime.h>
#include <hip/hip_bf16.h>

typedef _Float16 f16x8 __attribute__((ext_vector_type(8)));
typedef float f32x4 __attribute__((ext_vector_type(4)));
typedef unsigned int u32x2 __attribute__((ext_vector_type(2)));

#define GLDS16(gp, lp)                                                        \
  __builtin_amdgcn_global_load_lds(                                           \
      (const __attribute__((address_space(1))) void*)(gp),                    \
      (__attribute__((address_space(3))) void*)(lp), 16, 0, 0)

__device__ __forceinline__ unsigned short f2h(float f) {
  _Float16 h = (_Float16)f;
  return __builtin_bit_cast(unsigned short, h);
}
__device__ __forceinline__ float h2f(unsigned short u) {
  return (float)__builtin_bit_cast(_Float16, u);
}

// ---------------- K1a: convert key0/value0/query0 f32 -> f16 ----------------
__global__ __launch_bounds__(256) void k_convert_in(
    const float* __restrict__ k0, const float* __restrict__ v0,
    const float* __restrict__ q0, unsigned short* __restrict__ dst) {
  const float* src = blockIdx.y == 0 ? k0 : (blockIdx.y == 1 ? v0 : q0);
  unsigned short* d = dst + (size_t)blockIdx.y * 4194304u;
  const float4* s4 = (const float4*)src;
  ushort4* d4 = (ushort4*)d;
  for (int i = blockIdx.x * 256 + threadIdx.x; i < 1048576; i += 1024 * 256) {
    float4 f = s4[i];
    ushort4 o;
    o.x = f2h(f.x); o.y = f2h(f.y); o.z = f2h(f.z); o.w = f2h(f.w);
    d4[i] = o;
  }
}

// ------------- K1b: weights f32 [256][512] -> f16 transposed [512][256] -----
__global__ __launch_bounds__(256) void k_convert_w(
    const float* __restrict__ Wk, const float* __restrict__ Wv,
    const float* __restrict__ Wq, const float* __restrict__ Wr,
    unsigned short* __restrict__ WT) {
  int o = blockIdx.x * 256 + threadIdx.x;  // 0..524287
  int mat = o >> 17, rem = o & 131071;
  int n = rem >> 8, k = rem & 255;
  const float* W = mat == 0 ? Wk : mat == 1 ? Wv : mat == 2 ? Wq : Wr;
  WT[o] = f2h(W[k * 512 + n]);
}

// ---------------- K2: 4 projection GEMMs, f16 MFMA ----------------
// C[16384,512] = A[16384,256] * W[256,512] + bias ; mat: 0=K,1=V(->Vt),2=Q(scaled),3=R
// 1-D grid, XCD-bijective: the 4 n-tiles of one (m,mat) panel share an XCD.
__global__ __launch_bounds__(256) void k_gemm(
    const unsigned short* __restrict__ Ab, const unsigned short* __restrict__ WT,
    const float* __restrict__ bk, const float* __restrict__ bv,
    const float* __restrict__ bq, const float* __restrict__ br,
    unsigned short* __restrict__ Kb, unsigned short* __restrict__ Vt,
    unsigned short* __restrict__ Qb, unsigned short* __restrict__ Rh) {
  const float CS = 0.70710678118654752f * 1.44269504088896341f;
  int b = blockIdx.x;
  int id2 = (b & 7) * 256 + (b >> 3);       // XCD c owns id2 in [c*256,(c+1)*256)
  int nx = id2 & 3, my = (id2 >> 2) & 127, mat = id2 >> 9;
  const unsigned short* A = Ab + (size_t)(mat == 3 ? 2 : mat) * 4194304u;
  const unsigned short* Wm = WT + mat * 131072;
  const float* bias = mat == 0 ? bk : mat == 1 ? bv : mat == 2 ? bq : br;
  __shared__ unsigned short As[4096];  // [128][32]
  __shared__ unsigned short Bs[4096];  // [128 n][32 k]  (W^T tile)
  int m0 = my * 128, n0 = nx * 128;
  int tid = threadIdx.x, lane = tid & 63, w = tid >> 6;
  int wm = w >> 1, wn = w & 1, q = lane & 15, hi = lane >> 4;
  f32x4 acc[4][4];
#pragma unroll
  for (int i = 0; i < 4; ++i)
#pragma unroll
    for (int j = 0; j < 4; ++j) acc[i][j] = f32x4{0.f, 0.f, 0.f, 0.f};

  const unsigned short* gA = A + (m0 + (tid >> 2)) * 256 + (tid & 3) * 8;
  const unsigned short* gB = Wm + (n0 + (tid >> 2)) * 256 + (tid & 3) * 8;

  for (int kt = 0; kt < 8; ++kt) {
    __syncthreads();
    GLDS16(gA, &As[tid * 8]);
    GLDS16(gA + 64 * 256, &As[2048 + tid * 8]);
    GLDS16(gB, &Bs[tid * 8]);
    GLDS16(gB + 64 * 256, &Bs[2048 + tid * 8]);
    gA += 32; gB += 32;
    __syncthreads();
    f16x8 af[4], bf[4];
#pragma unroll
    for (int i = 0; i < 4; ++i)
      af[i] = *(const f16x8*)&As[(wm * 64 + i * 16 + q) * 32 + hi * 8];
#pragma unroll
    for (int j = 0; j < 4; ++j)
      bf[j] = *(const f16x8*)&Bs[(wn * 64 + j * 16 + q) * 32 + hi * 8];
#pragma unroll
    for (int i = 0; i < 4; ++i)
#pragma unroll
      for (int j = 0; j < 4; ++j)
        acc[i][j] = __builtin_amdgcn_mfma_f32_16x16x32_f16(af[i], bf[j], acc[i][j], 0, 0, 0);
  }

  float scale = (mat == 2) ? CS : 1.0f;
#pragma unroll
  for (int j = 0; j < 4; ++j) {
    int col = n0 + wn * 64 + j * 16 + q;
    float bs = bias[col];
#pragma unroll
    for (int i = 0; i < 4; ++i) {
      int rb = m0 + wm * 64 + i * 16 + 4 * hi;
#pragma unroll
      for (int r = 0; r < 4; ++r) {
        float v = (acc[i][j][r] + bs) * scale;
        int row = rb + r;
        if (mat == 1) {
          int gg = row >> 6, sl = row & 63, h = col >> 5, d = col & 31;
          Vt[gg * 32768 + d * 1024 + sl * 16 + h] = f2h(v);
        } else {
          unsigned short* C = mat == 0 ? Kb : mat == 2 ? Qb : Rh;
          C[row * 512 + col] = f2h(v);
        }
      }
    }
  }
}

// ---------------- K3: attention + residual + relu ----------------
// Static-shift softmax: p = exp2(s*CS - 24); softmax invariant to the shift.
// l via ones-MFMA row-sum. 64 q-rows per wave, 4 independent qt chains,
// no wave barriers (compiler orders P-scratch write->read via lgkmcnt).
__global__ __launch_bounds__(256, 4) void k_attn(
    const unsigned short* __restrict__ Kb, const unsigned short* __restrict__ Vt,
    const unsigned short* __restrict__ Qb, const unsigned short* __restrict__ Rh,
    float* __restrict__ out) {
  int p = blockIdx.x;                 // 1024 blocks = 4 per CU
  int id = (p & 7) * 128 + (p >> 3);  // XCD-bijective; group's 4 blocks share an XCD
  int g = id >> 2, sub = id & 3;
  int tid = threadIdx.x, lane = tid & 63, wid = tid >> 6;
  int q = lane & 15, hi = lane >> 4;
  int slice = sub * 4 + wid;          // 0..15 : 64 q-rows per wave
  const unsigned short* Qg = Qb + g * 32768 + slice * 2048;
  const unsigned short* Kg = Kb + g * 32768;
  const unsigned short* Vg = Vt + g * 32768;  // [32 d][1024 s]
  __shared__ unsigned short Pl[16][1024];     // [wave*4+qt][16 q][64], XOR-swizzled
  int swz = (q & 7) << 4;
  char* base = (char*)&Pl[wid * 4][0] + q * 128;
  int w0 = (hi * 8) ^ swz;    // write: ^ t*32
  int r0 = (hi * 16) ^ swz;   // read:  ^ c*64

  f16x8 qf[4];
#pragma unroll
  for (int t = 0; t < 4; ++t)
    qf[t] = *(const f16x8*)&Qg[(t * 16 + q) * 32 + hi * 8];

  f16x8 ones;
#pragma unroll
  for (int i = 0; i < 8; ++i) ones[i] = (_Float16)1.0f;

  f32x4 o[4][2];
#pragma unroll
  for (int a = 0; a < 4; ++a)
#pragma unroll
    for (int b2 = 0; b2 < 2; ++b2) o[a][b2] = f32x4{0.f, 0.f, 0.f, 0.f};
  f32x4 ol[4];
#pragma unroll
  for (int a = 0; a < 4; ++a) ol[a] = f32x4{0.f, 0.f, 0.f, 0.f};
  const f32x4 zed = {0.f, 0.f, 0.f, 0.f};

  const unsigned short* Kl = Kg + q * 32 + hi * 8;
  const unsigned short* Vl = Vg + q * 1024 + hi * 8;

#pragma unroll 2
  for (int kv = 0; kv < 16; ++kv) {
    f16x8 kf[4];
#pragma unroll
    for (int t = 0; t < 4; ++t)
      kf[t] = *(const f16x8*)(Kl + kv * 2048 + t * 512);
    f16x8 vf[2][2];
#pragma unroll
    for (int dt = 0; dt < 2; ++dt)
#pragma unroll
      for (int c = 0; c < 2; ++c)
        vf[dt][c] = *(const f16x8*)(Vl + dt * 16384 + kv * 64 + c * 32);

#pragma unroll
    for (int qt = 0; qt < 4; ++qt) {
      char* pq = base + qt * 2048;
      f32x4 st[4];
#pragma unroll
      for (int t = 0; t < 4; ++t)
        st[t] = __builtin_amdgcn_mfma_f32_16x16x32_f16(kf[t], qf[qt], zed, 0, 0, 0);

      unsigned int pp[8];
#pragma unroll
      for (int t = 0; t < 4; ++t) {
        float p0 = __builtin_amdgcn_exp2f(st[t][0] - 24.f);
        float p1 = __builtin_amdgcn_exp2f(st[t][1] - 24.f);
        float p2 = __builtin_amdgcn_exp2f(st[t][2] - 24.f);
        float p3 = __builtin_amdgcn_exp2f(st[t][3] - 24.f);
        pp[2 * t] = __builtin_bit_cast(unsigned int, __builtin_amdgcn_cvt_pkrtz(p0, p1));
        pp[2 * t + 1] = __builtin_bit_cast(unsigned int, __builtin_amdgcn_cvt_pkrtz(p2, p3));
      }

#pragma unroll
      for (int t = 0; t < 4; ++t)
        *(u32x2*)(pq + (w0 ^ (t * 32))) = u32x2{pp[2 * t], pp[2 * t + 1]};
      f16x8 pf0 = *(const f16x8*)(pq + r0);
      f16x8 pf1 = *(const f16x8*)(pq + (r0 ^ 64));
      o[qt][0] = __builtin_amdgcn_mfma_f32_16x16x32_f16(vf[0][0], pf0, o[qt][0], 0, 0, 0);
      o[qt][1] = __builtin_amdgcn_mfma_f32_16x16x32_f16(vf[1][0], pf0, o[qt][1], 0, 0, 0);
      ol[qt]   = __builtin_amdgcn_mfma_f32_16x16x32_f16(ones,     pf0, ol[qt],   0, 0, 0);
      o[qt][0] = __builtin_amdgcn_mfma_f32_16x16x32_f16(vf[0][1], pf1, o[qt][0], 0, 0, 0);
      o[qt][1] = __builtin_amdgcn_mfma_f32_16x16x32_f16(vf[1][1], pf1, o[qt][1], 0, 0, 0);
      ol[qt]   = __builtin_amdgcn_mfma_f32_16x16x32_f16(ones,     pf1, ol[qt],   0, 0, 0);
    }
  }

#pragma unroll
  for (int qt = 0; qt < 4; ++qt) {
    float iv = 1.0f / ol[qt][0];  // every lane holds l for its q
#pragma unroll
    for (int dt = 0; dt < 2; ++dt) {
      int off = g * 32768 + (slice * 64 + qt * 16 + q) * 32 + dt * 16 + hi * 4;
      ushort4 rr = *(const ushort4*)&Rh[off];
      f32x4 a = o[qt][dt];
      float4 ov;
      ov.x = fmaxf(h2f(rr.x) + a[0] * iv, 0.f);
      ov.y = fmaxf(h2f(rr.y) + a[1] * iv, 0.f);
      ov.z = fmaxf(h2f(rr.z) + a[2] * iv, 0.f);
      ov.w = fmaxf(h2f(rr.w) + a[3] * iv, 0.f);
      *(float4*)&out[off] = ov;
    }
  }
}

extern "C" void kernel_launch(void* const* d_in, const int* in_sizes, int n_in,
                              void* d_out, int out_size, void* d_ws, size_t ws_size,
                              hipStream_t stream) {
  const float* key0 = (const float*)d_in[0];
  const float* value0 = (const float*)d_in[1];
  const float* query0 = (const float*)d_in[2];
  const float* Wk = (const float*)d_in[3];
  const float* bk = (const float*)d_in[4];
  const float* Wv = (const float*)d_in[5];
  const float* bv = (const float*)d_in[6];
  const float* Wq = (const float*)d_in[7];
  const float* bq = (const float*)d_in[8];
  const float* Wr = (const float*)d_in[9];
  const float* br = (const float*)d_in[10];
  float* out = (float*)d_out;
  char* ws = (char*)d_ws;
  unsigned short* Kb = (unsigned short*)(ws);              // 16 MB f16 [16384,512]
  unsigned short* Vt = (unsigned short*)(ws + 16777216);   // 16 MB f16 [256][32][1024]
  unsigned short* Qb = (unsigned short*)(ws + 33554432);   // 16 MB f16 (pre-scaled)
  unsigned short* Rh = (unsigned short*)(ws + 50331648);   // 16 MB f16 [16384,512]
  unsigned short* Ab = (unsigned short*)(ws + 67108864);   // 24 MB f16 [3][16384,256]
  unsigned short* WT = (unsigned short*)(ws + 92274688);   // 1 MB f16 [4][512][256]

  k_convert_in<<<dim3(1024, 3), dim3(256), 0, stream>>>(key0, value0, query0, Ab);
  k_convert_w<<<dim3(2048), dim3(256), 0, stream>>>(Wk, Wv, Wq, Wr, WT);
  k_gemm<<<dim3(2048), dim3(256), 0, stream>>>(Ab, WT, bk, bv, bq, br, Kb, Vt, Qb, Rh);
  k_attn<<<dim3(1024), dim3(256), 0, stream>>>(Kb, Vt, Qb, Rh, out);
}

// Round 7
// 173.859 us; speedup vs baseline: 1.4646x; 1.4646x over previous
//
#include <hip/hip_runtime.h>
#include <hip/hip_bf16.h>

typedef _Float16 f16x8 __attribute__((ext_vector_type(8)));
typedef float f32x4 __attribute__((ext_vector_type(4)));
typedef unsigned int u32x2 __attribute__((ext_vector_type(2)));
typedef unsigned short us8 __attribute__((ext_vector_type(8)));

#define GLDS16(gp, lp)                                                        \
  __builtin_amdgcn_global_load_lds(                                           \
      (const __attribute__((address_space(1))) void*)(gp),                    \
      (__attribute__((address_space(3))) void*)(lp), 16, 0, 0)

__device__ __forceinline__ unsigned short f2h(float f) {
  _Float16 h = (_Float16)f;
  return __builtin_bit_cast(unsigned short, h);
}
__device__ __forceinline__ float h2f(unsigned short u) {
  return (float)__builtin_bit_cast(_Float16, u);
}

// ---------------- K1a: convert key0/value0/query0 f32 -> f16 ----------------
__global__ __launch_bounds__(256) void k_convert_in(
    const float* __restrict__ k0, const float* __restrict__ v0,
    const float* __restrict__ q0, unsigned short* __restrict__ dst) {
  const float* src = blockIdx.y == 0 ? k0 : (blockIdx.y == 1 ? v0 : q0);
  unsigned short* d = dst + (size_t)blockIdx.y * 4194304u;
  const float4* s4 = (const float4*)src;
  ushort4* d4 = (ushort4*)d;
  for (int i = blockIdx.x * 256 + threadIdx.x; i < 1048576; i += 1024 * 256) {
    float4 f = s4[i];
    ushort4 o;
    o.x = f2h(f.x); o.y = f2h(f.y); o.z = f2h(f.z); o.w = f2h(f.w);
    d4[i] = o;
  }
}

// ------------- K1b: weights f32 [256][512] -> f16 transposed [512][256] -----
__global__ __launch_bounds__(256) void k_convert_w(
    const float* __restrict__ Wk, const float* __restrict__ Wv,
    const float* __restrict__ Wq, const float* __restrict__ Wr,
    unsigned short* __restrict__ WT) {
  int o = blockIdx.x * 256 + threadIdx.x;  // 0..524287
  int mat = o >> 17, rem = o & 131071;
  int n = rem >> 8, k = rem & 255;
  const float* W = mat == 0 ? Wk : mat == 1 ? Wv : mat == 2 ? Wq : Wr;
  WT[o] = f2h(W[k * 512 + n]);
}

// ---------------- K2: 4 projection GEMMs, f16 MFMA ----------------
// C[16384,512] = A[16384,256] * W[256,512] + bias ; mat: 0=K,1=V,2=Q(scaled),3=R
// 1-D grid, XCD-bijective: the 4 n-tiles of one (m,mat) panel share an XCD.
__global__ __launch_bounds__(256) void k_gemm(
    const unsigned short* __restrict__ Ab, const unsigned short* __restrict__ WT,
    const float* __restrict__ bk, const float* __restrict__ bv,
    const float* __restrict__ bq, const float* __restrict__ br,
    unsigned short* __restrict__ Kb, unsigned short* __restrict__ Vh,
    unsigned short* __restrict__ Qb, unsigned short* __restrict__ Rh) {
  const float CS = 0.70710678118654752f * 1.44269504088896341f;
  int b = blockIdx.x;
  int id2 = (b & 7) * 256 + (b >> 3);       // XCD c owns id2 in [c*256,(c+1)*256)
  int nx = id2 & 3, my = (id2 >> 2) & 127, mat = id2 >> 9;
  const unsigned short* A = Ab + (size_t)(mat == 3 ? 2 : mat) * 4194304u;
  const unsigned short* Wm = WT + mat * 131072;
  const float* bias = mat == 0 ? bk : mat == 1 ? bv : mat == 2 ? bq : br;
  unsigned short* C = mat == 0 ? Kb : mat == 1 ? Vh : mat == 2 ? Qb : Rh;
  __shared__ unsigned short As[4096];  // [128][32]
  __shared__ unsigned short Bs[4096];  // [128 n][32 k]  (W^T tile)
  int m0 = my * 128, n0 = nx * 128;
  int tid = threadIdx.x, lane = tid & 63, w = tid >> 6;
  int wm = w >> 1, wn = w & 1, q = lane & 15, hi = lane >> 4;
  f32x4 acc[4][4];
#pragma unroll
  for (int i = 0; i < 4; ++i)
#pragma unroll
    for (int j = 0; j < 4; ++j) acc[i][j] = f32x4{0.f, 0.f, 0.f, 0.f};

  const unsigned short* gA = A + (m0 + (tid >> 2)) * 256 + (tid & 3) * 8;
  const unsigned short* gB = Wm + (n0 + (tid >> 2)) * 256 + (tid & 3) * 8;

  for (int kt = 0; kt < 8; ++kt) {
    __syncthreads();
    GLDS16(gA, &As[tid * 8]);
    GLDS16(gA + 64 * 256, &As[2048 + tid * 8]);
    GLDS16(gB, &Bs[tid * 8]);
    GLDS16(gB + 64 * 256, &Bs[2048 + tid * 8]);
    gA += 32; gB += 32;
    __syncthreads();
    f16x8 af[4], bf[4];
#pragma unroll
    for (int i = 0; i < 4; ++i)
      af[i] = *(const f16x8*)&As[(wm * 64 + i * 16 + q) * 32 + hi * 8];
#pragma unroll
    for (int j = 0; j < 4; ++j)
      bf[j] = *(const f16x8*)&Bs[(wn * 64 + j * 16 + q) * 32 + hi * 8];
#pragma unroll
    for (int i = 0; i < 4; ++i)
#pragma unroll
      for (int j = 0; j < 4; ++j)
        acc[i][j] = __builtin_amdgcn_mfma_f32_16x16x32_f16(af[i], bf[j], acc[i][j], 0, 0, 0);
  }

  float scale = (mat == 2) ? CS : 1.0f;
#pragma unroll
  for (int j = 0; j < 4; ++j) {
    int col = n0 + wn * 64 + j * 16 + q;
    float bs = bias[col];
#pragma unroll
    for (int i = 0; i < 4; ++i) {
      int rb = m0 + wm * 64 + i * 16 + 4 * hi;
#pragma unroll
      for (int r = 0; r < 4; ++r) {
        float v = (acc[i][j][r] + bs) * scale;
        C[(rb + r) * 512 + col] = f2h(v);
      }
    }
  }
}

// -------- K2b: V transpose per group: Vt[g][d][s] = Vh(flat)[g][s][d] -------
__global__ __launch_bounds__(256) void k_vt(
    const unsigned short* __restrict__ Vh, unsigned short* __restrict__ Vt) {
  int t0 = blockIdx.x * 256 + threadIdx.x;  // 0..524287
#pragma unroll
  for (int it = 0; it < 2; ++it) {
    int c = t0 + it * 524288;  // chunk id 0..1048575 : 8 shorts each
    int s8 = c & 127, d = (c >> 7) & 31, g = c >> 12;  // g in [0,256)
    const unsigned short* src = Vh + g * 32768 + s8 * 256 + d;
    us8 v;
#pragma unroll
    for (int i = 0; i < 8; ++i) v[i] = src[i * 32];
    *(us8*)&Vt[g * 32768 + d * 1024 + s8 * 8] = v;
  }
}

// ---------------- K3: attention + residual + relu ----------------
// Static-shift softmax via MFMA C-init: st = K^T Q + (-24); p = exp2(st).
// l via ones-MFMA row-sum. K prefetched one tile ahead in registers.
__global__ __launch_bounds__(256, 4) void k_attn(
    const unsigned short* __restrict__ Kb, const unsigned short* __restrict__ Vt,
    const unsigned short* __restrict__ Qb, const unsigned short* __restrict__ Rh,
    float* __restrict__ out) {
  int p = blockIdx.x;
  int g = (p & 7) + 8 * (p >> 6);   // XCD-bijective: a group's 8 blocks share an XCD
  int sub = (p >> 3) & 7;
  int tid = threadIdx.x, lane = tid & 63, wid = tid >> 6;
  int q = lane & 15, hi = lane >> 4;
  int slice = sub * 4 + wid;        // 0..31 : 32 q-rows per wave
  const unsigned short* Qg = Qb + g * 32768 + slice * 1024;
  const unsigned short* Kg = Kb + g * 32768;
  const unsigned short* Vg = Vt + g * 32768;  // [32 d][1024 s]
  __shared__ unsigned short Pl[4][1024];      // per-wave P scratch [16 q][64], XOR-swizzled
  char* wr0 = (char*)&Pl[wid][0] + q * 128;
  int swz = (q & 7) << 4;
  int w0 = (hi * 8) ^ swz;    // write: ^ t*32
  int r0 = (hi * 16) ^ swz;   // read:  ^ c*64

  f16x8 qf[2];
#pragma unroll
  for (int t = 0; t < 2; ++t)
    qf[t] = *(const f16x8*)&Qg[(t * 16 + q) * 32 + hi * 8];

  f16x8 ones;
#pragma unroll
  for (int i = 0; i < 8; ++i) ones[i] = (_Float16)1.0f;

  f32x4 o[2][2];
#pragma unroll
  for (int a = 0; a < 2; ++a)
#pragma unroll
    for (int b2 = 0; b2 < 2; ++b2) o[a][b2] = f32x4{0.f, 0.f, 0.f, 0.f};
  f32x4 ol[2] = {f32x4{0.f, 0.f, 0.f, 0.f}, f32x4{0.f, 0.f, 0.f, 0.f}};
  const f32x4 neg24 = {-24.f, -24.f, -24.f, -24.f};

  const unsigned short* Kl = Kg + q * 32 + hi * 8;
  const unsigned short* Vl = Vg + q * 1024 + hi * 8;

  // K prefetch: kf holds tile kv, loaded one iteration ahead
  f16x8 kf[4];
#pragma unroll
  for (int t = 0; t < 4; ++t)
    kf[t] = *(const f16x8*)(Kl + t * 512);

  for (int kv = 0; kv < 16; ++kv) {
    int nx = (kv + 1) & 15;  // wraps on last iter (harmless reload of tile 0)
    f16x8 nkf[4];
#pragma unroll
    for (int t = 0; t < 4; ++t)
      nkf[t] = *(const f16x8*)(Kl + nx * 2048 + t * 512);
    f16x8 vf[2][2];
#pragma unroll
    for (int dt = 0; dt < 2; ++dt)
#pragma unroll
      for (int c = 0; c < 2; ++c)
        vf[dt][c] = *(const f16x8*)(Vl + dt * 16384 + kv * 64 + c * 32);

#pragma unroll
    for (int qt = 0; qt < 2; ++qt) {
      f32x4 st[4];
      __builtin_amdgcn_s_setprio(1);
#pragma unroll
      for (int t = 0; t < 4; ++t)
        st[t] = __builtin_amdgcn_mfma_f32_16x16x32_f16(kf[t], qf[qt], neg24, 0, 0, 0);
      __builtin_amdgcn_s_setprio(0);

      unsigned int pp[8];
#pragma unroll
      for (int t = 0; t < 4; ++t) {
        float p0 = __builtin_amdgcn_exp2f(st[t][0]);
        float p1 = __builtin_amdgcn_exp2f(st[t][1]);
        float p2 = __builtin_amdgcn_exp2f(st[t][2]);
        float p3 = __builtin_amdgcn_exp2f(st[t][3]);
        pp[2 * t] = __builtin_bit_cast(unsigned int, __builtin_amdgcn_cvt_pkrtz(p0, p1));
        pp[2 * t + 1] = __builtin_bit_cast(unsigned int, __builtin_amdgcn_cvt_pkrtz(p2, p3));
      }

#pragma unroll
      for (int t = 0; t < 4; ++t)
        *(u32x2*)(wr0 + (w0 ^ (t * 32))) = u32x2{pp[2 * t], pp[2 * t + 1]};
      __builtin_amdgcn_wave_barrier();
      f16x8 pf0 = *(const f16x8*)(wr0 + r0);
      f16x8 pf1 = *(const f16x8*)(wr0 + (r0 ^ 64));
      __builtin_amdgcn_s_setprio(1);
      o[qt][0] = __builtin_amdgcn_mfma_f32_16x16x32_f16(vf[0][0], pf0, o[qt][0], 0, 0, 0);
      o[qt][1] = __builtin_amdgcn_mfma_f32_16x16x32_f16(vf[1][0], pf0, o[qt][1], 0, 0, 0);
      ol[qt]   = __builtin_amdgcn_mfma_f32_16x16x32_f16(ones,     pf0, ol[qt],   0, 0, 0);
      o[qt][0] = __builtin_amdgcn_mfma_f32_16x16x32_f16(vf[0][1], pf1, o[qt][0], 0, 0, 0);
      o[qt][1] = __builtin_amdgcn_mfma_f32_16x16x32_f16(vf[1][1], pf1, o[qt][1], 0, 0, 0);
      ol[qt]   = __builtin_amdgcn_mfma_f32_16x16x32_f16(ones,     pf1, ol[qt],   0, 0, 0);
      __builtin_amdgcn_s_setprio(0);
      __builtin_amdgcn_wave_barrier();
    }
#pragma unroll
    for (int t = 0; t < 4; ++t) kf[t] = nkf[t];
  }

#pragma unroll
  for (int qt = 0; qt < 2; ++qt) {
    float iv = 1.0f / ol[qt][0];  // every lane holds l for its q
#pragma unroll
    for (int dt = 0; dt < 2; ++dt) {
      int off = g * 32768 + (slice * 32 + qt * 16 + q) * 32 + dt * 16 + hi * 4;
      ushort4 rr = *(const ushort4*)&Rh[off];
      f32x4 a = o[qt][dt];
      float4 ov;
      ov.x = fmaxf(h2f(rr.x) + a[0] * iv, 0.f);
      ov.y = fmaxf(h2f(rr.y) + a[1] * iv, 0.f);
      ov.z = fmaxf(h2f(rr.z) + a[2] * iv, 0.f);
      ov.w = fmaxf(h2f(rr.w) + a[3] * iv, 0.f);
      *(float4*)&out[off] = ov;
    }
  }
}

extern "C" void kernel_launch(void* const* d_in, const int* in_sizes, int n_in,
                              void* d_out, int out_size, void* d_ws, size_t ws_size,
                              hipStream_t stream) {
  const float* key0 = (const float*)d_in[0];
  const float* value0 = (const float*)d_in[1];
  const float* query0 = (const float*)d_in[2];
  const float* Wk = (const float*)d_in[3];
  const float* bk = (const float*)d_in[4];
  const float* Wv = (const float*)d_in[5];
  const float* bv = (const float*)d_in[6];
  const float* Wq = (const float*)d_in[7];
  const float* bq = (const float*)d_in[8];
  const float* Wr = (const float*)d_in[9];
  const float* br = (const float*)d_in[10];
  float* out = (float*)d_out;
  char* ws = (char*)d_ws;
  unsigned short* Kb = (unsigned short*)(ws);              // 16 MB f16 [16384,512]
  unsigned short* Vt = (unsigned short*)(ws + 16777216);   // 16 MB f16 [256][32][1024]
  unsigned short* Qb = (unsigned short*)(ws + 33554432);   // 16 MB f16 (pre-scaled)
  unsigned short* Rh = (unsigned short*)(ws + 50331648);   // 16 MB f16 [16384,512]
  unsigned short* Ab = (unsigned short*)(ws + 67108864);   // 24 MB f16 [3][16384,256]
  unsigned short* WT = (unsigned short*)(ws + 92274688);   // 1 MB f16 [4][512][256]
  unsigned short* Vh = (unsigned short*)(ws + 93323264);   // 16 MB f16 [16384,512]

  k_convert_in<<<dim3(1024, 3), dim3(256), 0, stream>>>(key0, value0, query0, Ab);
  k_convert_w<<<dim3(2048), dim3(256), 0, stream>>>(Wk, Wv, Wq, Wr, WT);
  k_gemm<<<dim3(2048), dim3(256), 0, stream>>>(Ab, WT, bk, bv, bq, br, Kb, Vh, Qb, Rh);
  k_vt<<<dim3(2048), dim3(256), 0, stream>>>(Vh, Vt);
  k_attn<<<dim3(2048), dim3(256), 0, stream>>>(Kb, Vt, Qb, Rh, out);
}